// Round 17
// baseline (368.288 us; speedup 1.0000x reference)
//
#include <hip/hip_runtime.h>
#include <hip/hip_fp16.h>
#include <math.h>

typedef unsigned long long u64;
typedef __attribute__((ext_vector_type(2))) _Float16 half2v;
typedef __attribute__((ext_vector_type(4))) _Float16 half4v;

// ============================================================================
// CSR build v5: partition into per-bucket queues (64 dsts/bucket, fixed CAP),
// then k_build with FIXED per-bucket csr spans (csrbase = b*MAXSPAN) -- no
// global scan stage at all. Row range packed as u64 rs2[d] = e0 | (e1<<32).
// Partition PEPB=16384 (~21-edge runs/bucket -> full write sectors).
// Edge phase: wave per dst, 16-lane x 4-edge packed fp16, unroll x4.
// Head fused into pool via last-block-done counter.
// ============================================================================

#define CAP     3008    // queue slots per bucket (mean ~2046)
#define MAXSPAN 3072    // fixed csr slots per bucket (edges + 64 self-loops)
#define PEPB    16384   // edges per partition block (long runs per bucket)

// ---------- node transform core: 64 nodes/block, 16 nodes/wave, fp16 rows ----------
__device__ __forceinline__ void xf_block(
        const float* __restrict__ h, int ld,
        const float* __restrict__ Wl, const float* __restrict__ bl,
        const float* __restrict__ Wr, const float* __restrict__ br,
        __half* __restrict__ xl, __half* __restrict__ xr,
        int N, int node0, _Float16* rows, int t) {
    int in_dim = 1 << ld;
    int q = in_dim >> 2;            // 4-element chunks per row
    for (int idx = t; idx < 64 * q; idx += 256) {
        int nn = idx >> (ld - 2);
        int kk = (idx & (q - 1)) << 2;
        int node = node0 + nn;
        float4 v = {0.f, 0.f, 0.f, 0.f};
        if (node < N) v = *(const float4*)(h + (((size_t)node) << ld) + kk);
        half4v hv = {(_Float16)v.x, (_Float16)v.y, (_Float16)v.z, (_Float16)v.w};
        *(half4v*)(rows + (nn << ld) + kk) = hv;
    }
    __syncthreads();
    int lane = t & 63, w = t >> 6;
    int nb = w * 16;
    float al[16], ar[16];
    float blv = bl[lane], brv = br[lane];
#pragma unroll
    for (int i = 0; i < 16; ++i) { al[i] = blv; ar[i] = brv; }
    for (int k = 0; k < in_dim; k += 4) {
        float wl0 = Wl[(k + 0) * 64 + lane], wl1 = Wl[(k + 1) * 64 + lane];
        float wl2 = Wl[(k + 2) * 64 + lane], wl3 = Wl[(k + 3) * 64 + lane];
        float wr0 = Wr[(k + 0) * 64 + lane], wr1 = Wr[(k + 1) * 64 + lane];
        float wr2 = Wr[(k + 2) * 64 + lane], wr3 = Wr[(k + 3) * 64 + lane];
#pragma unroll
        for (int i = 0; i < 16; ++i) {
            half4v r = *(const half4v*)(rows + ((nb + i) << ld) + k);  // broadcast
            al[i] = fmaf((float)r.x, wl0, al[i]); al[i] = fmaf((float)r.y, wl1, al[i]);
            al[i] = fmaf((float)r.z, wl2, al[i]); al[i] = fmaf((float)r.w, wl3, al[i]);
            ar[i] = fmaf((float)r.x, wr0, ar[i]); ar[i] = fmaf((float)r.y, wr1, ar[i]);
            ar[i] = fmaf((float)r.z, wr2, ar[i]); ar[i] = fmaf((float)r.w, wr3, ar[i]);
        }
    }
#pragma unroll
    for (int i = 0; i < 16; ++i) {
        int node = node0 + nb + i;
        if (node < N) {
            xl[((size_t)node << 6) + lane] = __float2half(al[i]);
            xr[((size_t)node << 6) + lane] = __float2half(ar[i]);
        }
    }
}

// shared-memory union: xf rows (16 KB) vs partition arrays (9.6 KB)
union XfPartSmem {
    _Float16 rows[64 * 128];
    struct { int lh[800]; int lbase[800]; int lcur[800]; } p;
};

// FUSED: blocks [0,nbXF) = layer-1 node transform; blocks [nbXF,..) = partition
__global__ void k_xf1_part(
        const float* __restrict__ h, int ld,
        const float* __restrict__ Wl, const float* __restrict__ bl,
        const float* __restrict__ Wr, const float* __restrict__ br,
        __half* __restrict__ xl, __half* __restrict__ xr, int N, int nbXF,
        const int* __restrict__ ei, const float* __restrict__ ea,
        int* __restrict__ qtail, u64* __restrict__ queue, int E, int NB) {
    __shared__ XfPartSmem sm;
    int t = threadIdx.x;
    if (blockIdx.x < nbXF) {
        xf_block(h, ld, Wl, bl, Wr, br, xl, xr, N, blockIdx.x * 64, sm.rows, t);
    } else {
        int pb = blockIdx.x - nbXF;
        for (int i = t; i < NB; i += 256) { sm.p.lh[i] = 0; sm.p.lcur[i] = 0; }
        __syncthreads();
        int base = pb * PEPB;
        int end = base + PEPB; if (end > E) end = E;
        for (int e = base + t; e < end; e += 256) {
            int d = ei[E + e];
            atomicAdd(&sm.p.lh[d >> 6], 1);
        }
        __syncthreads();
        for (int i = t; i < NB; i += 256)
            if (sm.p.lh[i]) sm.p.lbase[i] = atomicAdd(&qtail[i], sm.p.lh[i]);
        __syncthreads();
        for (int e = base + t; e < end; e += 256) {
            int d = ei[E + e];
            int src = ei[e];
            float a = ea[e];
            int b = d >> 6;
            int idx = atomicAdd(&sm.p.lcur[b], 1);
            unsigned aq = (unsigned)(a * 16777216.0f);    // fixed-24, attr in [0,1)
            queue[(size_t)b * CAP + sm.p.lbase[b] + idx] =
                (((u64)aq) << 24) | (((u64)(d & 63)) << 17) | (unsigned)src;
        }
    }
}

__device__ __forceinline__ unsigned attr_q15(float a) {
    unsigned short hb = __builtin_bit_cast(unsigned short, (_Float16)a);
    return (unsigned)(hb >> 1);       // attr in [0,1) -> fp16 top bit 0
}

// one block per 64-dst bucket: count+local-scan+scatter in LDS, coalesced flush
// csr base is FIXED at b*MAXSPAN -- no global scan dependency.
__global__ void k_build(const u64* __restrict__ queue, const int* __restrict__ qtail,
                        u64* __restrict__ rs2, unsigned* __restrict__ csr, int N) {
    __shared__ u64 stat[64];
    __shared__ int fill[64], sc[64];
    __shared__ unsigned lcsr[MAXSPAN];
    int t = threadIdx.x, b = blockIdx.x;
    if (t < 64) stat[t] = 0;
    __syncthreads();
    int cnt = qtail[b];
    size_t q0 = (size_t)b * CAP;
    for (int i = t; i < cnt; i += 256) {
        u64 r = queue[q0 + i];
        int dl = (int)((r >> 17) & 63);
        atomicAdd(&stat[dl], (1ULL << 32) | (unsigned)(r >> 24));
    }
    __syncthreads();
    int dg = (b << 6) + t;
    u64 p = (t < 64) ? stat[t] : 0;
    int deg = (int)(p >> 32);
    int v = (t < 64 && dg < N) ? deg + 1 : 0;
    if (t < 64) sc[t] = v;
    __syncthreads();
    for (int off = 1; off < 64; off <<= 1) {
        int a = (t >= off && t < 64) ? sc[t - off] : 0;
        __syncthreads();
        if (t < 64) sc[t] += a;
        __syncthreads();
    }
    int c0 = b * MAXSPAN;
    if (t < 64 && dg < N) {
        int basel = sc[t] - v;   // exclusive
        rs2[dg] = (u64)(unsigned)(c0 + basel) | (((u64)(unsigned)(c0 + basel + deg + 1)) << 32);
        fill[t] = basel;
        float mean = ((float)(unsigned)p * (1.0f / 16777216.0f)) / fmaxf((float)deg, 1.0f);
        if (basel + deg < MAXSPAN) lcsr[basel + deg] = (attr_q15(mean) << 17) | (unsigned)dg;
    }
    __syncthreads();
    for (int i = t; i < cnt; i += 256) {
        u64 r = queue[q0 + i];
        int dl = (int)((r >> 17) & 63);
        int pos = atomicAdd(&fill[dl], 1);
        float av = (float)(unsigned)(r >> 24) * (1.0f / 16777216.0f);
        if (pos < MAXSPAN) lcsr[pos] = (attr_q15(av) << 17) | (unsigned)(r & 0x1FFFFu);
    }
    __syncthreads();
    int span = sc[63];               // total slots used in this bucket
    if (span > MAXSPAN) span = MAXSPAN;
    for (int j = t; j < span; j += 256) csr[c0 + j] = lcsr[j];
}

// ---------- node transform (standalone, layer 2: ld=6 -> 8 KB rows) ----------
__global__ void k_node_xf(const float* __restrict__ h, int ld,
                          const float* __restrict__ Wl, const float* __restrict__ bl,
                          const float* __restrict__ Wr, const float* __restrict__ br,
                          __half* __restrict__ xl, __half* __restrict__ xr, int N) {
    __shared__ _Float16 rows[64 * 64];
    xf_block(h, ld, Wl, bl, Wr, br, xl, xr, N, blockIdx.x * 64, rows, threadIdx.x);
}

// ---------- edge micro-step: one 4-edge group ----------
#define EDGE_GROUP(r, xh, cc)                                                  \
    {                                                                          \
        _Float16 ah = __builtin_bit_cast(_Float16, (unsigned short)((r >> 16) & 0xFFFEu)); \
        half2v aa = {ah, ah};                                                  \
        half2v x01 = {xh.x, xh.y}, x23 = {xh.z, xh.w};                         \
        half2v v01 = aa * We01 + (x01 + xr01);                                 \
        half2v v23 = aa * We23 + (x23 + xr23);                                 \
        half2v s01 = __builtin_elementwise_max(v01, v01 * k02);                \
        half2v s23 = __builtin_elementwise_max(v23, v23 * k02);                \
        cc = __builtin_amdgcn_fdot2(s01, at01, 0.f, false);                    \
        cc = __builtin_amdgcn_fdot2(s23, at23, cc, false);                     \
    }

// ---------- fused edge phase: wave/dst, 16x4 packed fp16, unroll x4 ----------
__global__ void k_attn(const __half* __restrict__ xl, const __half* __restrict__ xr,
                       const unsigned* __restrict__ csr, const u64* __restrict__ rs2,
                       const float* __restrict__ We, const float* __restrict__ att,
                       const float* __restrict__ bias,
                       float* __restrict__ hout, int N) {
    int lane = threadIdx.x & 63;
    int d = (int)(((size_t)blockIdx.x * blockDim.x + threadIdx.x) >> 6);
    if (d >= N) return;
    int eq = lane >> 4;           // which of 4 concurrent edges
    int fl = lane & 15;           // which 4-dim chunk of the 64 dims
    float4 Wef  = *(const float4*)(We + fl * 4);
    float4 attf = *(const float4*)(att + fl * 4);
    half2v We01 = {(_Float16)Wef.x, (_Float16)Wef.y};
    half2v We23 = {(_Float16)Wef.z, (_Float16)Wef.w};
    half2v at01 = {(_Float16)attf.x, (_Float16)attf.y};
    half2v at23 = {(_Float16)attf.z, (_Float16)attf.w};
    half4v xrh = *(const half4v*)(xr + ((size_t)d << 6) + fl * 4);
    half2v xr01 = {xrh.x, xrh.y}, xr23 = {xrh.z, xrh.w};
    const half2v k02 = {(_Float16)0.2f, (_Float16)0.2f};
    u64 rr = rs2[d];
    int e0 = __builtin_amdgcn_readfirstlane((int)(unsigned)rr);
    int e1 = __builtin_amdgcn_readfirstlane((int)(unsigned)(rr >> 32));
    float l = 0.f;
    float4 O = {0.f, 0.f, 0.f, 0.f};
    int e = e0;
    for (; e + 16 <= e1; e += 16) {     // 16 edges in flight
        unsigned rA = csr[e + eq];
        unsigned rB = csr[e + 4 + eq];
        unsigned rC = csr[e + 8 + eq];
        unsigned rD = csr[e + 12 + eq];
        half4v xA = *(const half4v*)(xl + (((size_t)(rA & 0x1FFFFu)) << 6) + fl * 4);
        half4v xB = *(const half4v*)(xl + (((size_t)(rB & 0x1FFFFu)) << 6) + fl * 4);
        half4v xC = *(const half4v*)(xl + (((size_t)(rC & 0x1FFFFu)) << 6) + fl * 4);
        half4v xD = *(const half4v*)(xl + (((size_t)(rD & 0x1FFFFu)) << 6) + fl * 4);
        float cA, cB, cC, cD;
        EDGE_GROUP(rA, xA, cA);
        EDGE_GROUP(rB, xB, cB);
        EDGE_GROUP(rC, xC, cC);
        EDGE_GROUP(rD, xD, cD);
#pragma unroll
        for (int mm = 1; mm <= 8; mm <<= 1) {      // 4 interleaved butterflies
            cA += __shfl_xor(cA, mm, 64);
            cB += __shfl_xor(cB, mm, 64);
            cC += __shfl_xor(cC, mm, 64);
            cD += __shfl_xor(cD, mm, 64);
        }
        float qA = __expf(cA), qB = __expf(cB), qC = __expf(cC), qD = __expf(cD);
        l += (qA + qB) + (qC + qD);
        O.x = fmaf(qA, (float)xA.x, O.x); O.x = fmaf(qB, (float)xB.x, O.x);
        O.x = fmaf(qC, (float)xC.x, O.x); O.x = fmaf(qD, (float)xD.x, O.x);
        O.y = fmaf(qA, (float)xA.y, O.y); O.y = fmaf(qB, (float)xB.y, O.y);
        O.y = fmaf(qC, (float)xC.y, O.y); O.y = fmaf(qD, (float)xD.y, O.y);
        O.z = fmaf(qA, (float)xA.z, O.z); O.z = fmaf(qB, (float)xB.z, O.z);
        O.z = fmaf(qC, (float)xC.z, O.z); O.z = fmaf(qD, (float)xD.z, O.z);
        O.w = fmaf(qA, (float)xA.w, O.w); O.w = fmaf(qB, (float)xB.w, O.w);
        O.w = fmaf(qC, (float)xC.w, O.w); O.w = fmaf(qD, (float)xD.w, O.w);
    }
    for (; e < e1; e += 4) {            // tail with clamp
        int ee = e + eq;
        bool valid = ee < e1;
        unsigned r = csr[valid ? ee : (e1 - 1)];
        half4v xh = *(const half4v*)(xl + (((size_t)(r & 0x1FFFFu)) << 6) + fl * 4);
        float c;
        EDGE_GROUP(r, xh, c);
#pragma unroll
        for (int mm = 1; mm <= 8; mm <<= 1) c += __shfl_xor(c, mm, 64);
        float q = valid ? __expf(c) : 0.f;
        l += q;
        O.x = fmaf(q, (float)xh.x, O.x);
        O.y = fmaf(q, (float)xh.y, O.y);
        O.z = fmaf(q, (float)xh.z, O.z);
        O.w = fmaf(q, (float)xh.w, O.w);
    }
#pragma unroll
    for (int mm = 16; mm <= 32; mm <<= 1) {
        l   += __shfl_xor(l, mm, 64);
        O.x += __shfl_xor(O.x, mm, 64);
        O.y += __shfl_xor(O.y, mm, 64);
        O.z += __shfl_xor(O.z, mm, 64);
        O.w += __shfl_xor(O.w, mm, 64);
    }
    if (eq == 0) {
        float inv = 1.0f / (l + 1e-16f);
        float4 b4 = *(const float4*)(bias + fl * 4);
        float4 res;
        res.x = fmaf(O.x, inv, b4.x);
        res.y = fmaf(O.y, inv, b4.y);
        res.z = fmaf(O.z, inv, b4.z);
        res.w = fmaf(O.w, inv, b4.w);
        res.x = res.x > 0.f ? res.x : expm1f(res.x);
        res.y = res.y > 0.f ? res.y : expm1f(res.y);
        res.z = res.z > 0.f ? res.z : expm1f(res.z);
        res.w = res.w > 0.f ? res.w : expm1f(res.w);
        *(float4*)(hout + ((size_t)d << 6) + fl * 4) = res;
    }
}

// ---------- pool (+ fused head in last-done block) ----------
__global__ void k_pool_head(const float* __restrict__ h, const int* __restrict__ batch,
                            float* __restrict__ pooled, float* __restrict__ gcnt,
                            int N, int npw, int* __restrict__ done,
                            const float* __restrict__ W1, const float* __restrict__ b1,
                            const float* __restrict__ gam, const float* __restrict__ bet,
                            const float* __restrict__ mu, const float* __restrict__ var,
                            const float* __restrict__ W3, const float* __restrict__ b3,
                            float* __restrict__ out, int G) {
    int tid = threadIdx.x;
    int lane = tid & 63;
    int wave = (int)(((size_t)blockIdx.x * blockDim.x + tid) >> 6);
    int begin = wave * npw;
    if (begin < N) {
        int end = begin + npw; if (end > N) end = N;
        int g = batch[begin];
        float acc = 0.f, cnt = 0.f;
        for (int n = begin; n < end; ++n) {
            int gn = batch[n];
            if (gn != g) {
                atomicAdd(&pooled[((size_t)g << 6) + lane], acc);
                if (lane == 0) atomicAdd(&gcnt[g], cnt);
                g = gn; acc = 0.f; cnt = 0.f;
            }
            acc += h[((size_t)n << 6) + lane];
            cnt += 1.f;
        }
        atomicAdd(&pooled[((size_t)g << 6) + lane], acc);
        if (lane == 0) atomicAdd(&gcnt[g], cnt);
    }
    __threadfence();
    __syncthreads();
    __shared__ int lastFlag;
    if (tid == 0) lastFlag = (atomicAdd(done, 1) == (int)gridDim.x - 1);
    __syncthreads();
    if (lastFlag && tid < G) {
        __threadfence();
        int g = tid;
        float inv = 1.0f / fmaxf(gcnt[g], 1.0f);
        float pr[64];
        for (int k = 0; k < 64; ++k) pr[k] = pooled[((size_t)g << 6) + k] * inv;
        float o = b3[0];
        for (int j = 0; j < 32; ++j) {
            float z = b1[j];
            for (int k = 0; k < 64; ++k) z += pr[k] * W1[k * 32 + j];
            z = fmaxf(z, 0.f);
            z = (z - mu[j]) / sqrtf(var[j] + 1e-5f) * gam[j] + bet[j];
            o += z * W3[j];
        }
        out[g] = o;
    }
}

// ---------- launch ----------
extern "C" void kernel_launch(void* const* d_in, const int* in_sizes, int n_in,
                              void* d_out, int out_size, void* d_ws, size_t ws_size,
                              hipStream_t stream) {
    const float* x    = (const float*)d_in[0];
    const int*   ei   = (const int*)d_in[1];
    const float* ea   = (const float*)d_in[2];
    const int*   batch= (const int*)d_in[3];
    const float* Wl1  = (const float*)d_in[4];
    const float* bl1  = (const float*)d_in[5];
    const float* Wr1  = (const float*)d_in[6];
    const float* br1  = (const float*)d_in[7];
    const float* We1  = (const float*)d_in[8];
    const float* att1 = (const float*)d_in[9];
    const float* bi1  = (const float*)d_in[10];
    const float* Wl2  = (const float*)d_in[11];
    const float* bl2  = (const float*)d_in[12];
    const float* Wr2  = (const float*)d_in[13];
    const float* br2  = (const float*)d_in[14];
    const float* We2  = (const float*)d_in[15];
    const float* att2 = (const float*)d_in[16];
    const float* bi2  = (const float*)d_in[17];
    const float* Wf1  = (const float*)d_in[18];
    const float* bf1  = (const float*)d_in[19];
    const float* gam  = (const float*)d_in[20];
    const float* bet  = (const float*)d_in[21];
    const float* mu   = (const float*)d_in[22];
    const float* var  = (const float*)d_in[23];
    const float* Wf3  = (const float*)d_in[24];
    const float* bf3  = (const float*)d_in[25];

    const int N    = in_sizes[3];          // 50000
    const int E    = in_sizes[2];          // 1600000
    const int INd  = in_sizes[0] / N;      // 128
    const int ld1  = (INd == 128) ? 7 : 6;
    const int G    = out_size;             // 64
    const int NB   = (N + 63) / 64;        // 64-dst buckets

    // workspace carve-up (256B aligned)
    char* w = (char*)d_ws;
    auto carve = [&](size_t bytes) { char* p = w; w += (bytes + 255) & ~(size_t)255; return p; };
    __half*   xl       = (__half*)  carve((size_t)N * 64 * 2);
    __half*   xr       = (__half*)  carve((size_t)N * 64 * 2);
    float*    hbuf     = (float*)   carve((size_t)N * 64 * 4);
    unsigned* csr      = (unsigned*)carve((size_t)NB * MAXSPAN * 4);
    u64*      queue    = (u64*)     carve((size_t)NB * CAP * 8);
    u64*      rs2      = (u64*)     carve((size_t)N * 8);
    int*      qtail    = (int*)     carve((size_t)(NB + 1) * 4);
    float*    pooled   = (float*)   carve((size_t)G * 64 * 4);   // contiguous with
    float*    gcnt     = (float*)   carve((size_t)G * 4);        // gcnt and done:
    int*      done     = (int*)     carve(256);                  // single memset

    const int TB = 256;
    const int nbXF = (N + 63) / 64;              // node-transform blocks
    const int attnBlocks = (N + 3) / 4;          // wave per dst, 4 waves/block
    const int nbPart = (E + PEPB - 1) / PEPB;

    // ---- zero counters (one memset each; pooled/gcnt/done are contiguous) ----
    hipMemsetAsync(qtail, 0, (size_t)(NB + 1) * 4, stream);
    size_t poolRegion = ((size_t)G * 64 * 4 + 255 & ~(size_t)255)
                      + ((size_t)G * 4 + 255 & ~(size_t)255) + 256;
    hipMemsetAsync(pooled, 0, poolRegion, stream);

    // ---- fused: layer-1 node transform || edge partition ----
    k_xf1_part<<<nbXF + nbPart, TB, 0, stream>>>(x, ld1, Wl1, bl1, Wr1, br1, xl, xr, N, nbXF,
                                                 ei, ea, qtail, queue, E, NB);
    k_build<<<NB, TB, 0, stream>>>(queue, qtail, rs2, csr, N);

    // ---- layer 1 edge phase ----
    k_attn<<<attnBlocks, TB, 0, stream>>>(xl, xr, csr, rs2, We1, att1, bi1, hbuf, N);

    // ---- layer 2 ----
    k_node_xf<<<nbXF, TB, 0, stream>>>(hbuf, 6, Wl2, bl2, Wr2, br2, xl, xr, N);
    k_attn<<<attnBlocks, TB, 0, stream>>>(xl, xr, csr, rs2, We2, att2, bi2, hbuf, N);

    // ---- pool + head (fused) ----
    const int npw = 64;
    const int poolWaves = (N + npw - 1) / npw;
    k_pool_head<<<(poolWaves * 64 + TB - 1) / TB, TB, 0, stream>>>(
        hbuf, batch, pooled, gcnt, N, npw, done,
        Wf1, bf1, gam, bet, mu, var, Wf3, bf3, (float*)d_out, G);
}

// Round 18
// 355.187 us; speedup vs baseline: 1.0369x; 1.0369x over previous
//
#include <hip/hip_runtime.h>
#include <hip/hip_fp16.h>
#include <math.h>

typedef unsigned long long u64;
typedef __attribute__((ext_vector_type(2))) _Float16 half2v;
typedef __attribute__((ext_vector_type(4))) _Float16 half4v;

// ============================================================================
// CSR build v6 (best measured combo):
//  - partition: PEPB=4096, 256-dst buckets (16-edge runs -> full sectors)
//  - NO scan stage: fixed csr span per bucket (csrbase = b*MAXSPAN)
//  - k_build: 196 blocks x 1024 threads, all-LDS count/scan/scatter, flush
// Queue record u64: [48:25]=attr fixed-24, [24:17]=dst&255, [16:0]=src.
// csr record u32: [31:17]=fp16-attr-bits>>1, [16:0]=src.
// Row range packed u64 rs2[d] = e0 | (e1<<32).
// Edge phase: wave per dst, 16-lane x 4-edge packed fp16, unroll x4.
// Head fused into pool via last-block-done counter.
// ============================================================================

#define CAP     12032   // queue slots per 256-dst bucket (mean ~8163)
#define MAXSPAN 12288   // fixed csr slots per bucket (edges + 256 self-loops)
#define PEPB    4096    // edges per partition block

// ---------- node transform core: 64 nodes/block, 16 nodes/wave, fp16 rows ----------
__device__ __forceinline__ void xf_block(
        const float* __restrict__ h, int ld,
        const float* __restrict__ Wl, const float* __restrict__ bl,
        const float* __restrict__ Wr, const float* __restrict__ br,
        __half* __restrict__ xl, __half* __restrict__ xr,
        int N, int node0, _Float16* rows, int t) {
    int in_dim = 1 << ld;
    int q = in_dim >> 2;            // 4-element chunks per row
    for (int idx = t; idx < 64 * q; idx += 256) {
        int nn = idx >> (ld - 2);
        int kk = (idx & (q - 1)) << 2;
        int node = node0 + nn;
        float4 v = {0.f, 0.f, 0.f, 0.f};
        if (node < N) v = *(const float4*)(h + (((size_t)node) << ld) + kk);
        half4v hv = {(_Float16)v.x, (_Float16)v.y, (_Float16)v.z, (_Float16)v.w};
        *(half4v*)(rows + (nn << ld) + kk) = hv;
    }
    __syncthreads();
    int lane = t & 63, w = t >> 6;
    int nb = w * 16;
    float al[16], ar[16];
    float blv = bl[lane], brv = br[lane];
#pragma unroll
    for (int i = 0; i < 16; ++i) { al[i] = blv; ar[i] = brv; }
    for (int k = 0; k < in_dim; k += 4) {
        float wl0 = Wl[(k + 0) * 64 + lane], wl1 = Wl[(k + 1) * 64 + lane];
        float wl2 = Wl[(k + 2) * 64 + lane], wl3 = Wl[(k + 3) * 64 + lane];
        float wr0 = Wr[(k + 0) * 64 + lane], wr1 = Wr[(k + 1) * 64 + lane];
        float wr2 = Wr[(k + 2) * 64 + lane], wr3 = Wr[(k + 3) * 64 + lane];
#pragma unroll
        for (int i = 0; i < 16; ++i) {
            half4v r = *(const half4v*)(rows + ((nb + i) << ld) + k);  // broadcast
            al[i] = fmaf((float)r.x, wl0, al[i]); al[i] = fmaf((float)r.y, wl1, al[i]);
            al[i] = fmaf((float)r.z, wl2, al[i]); al[i] = fmaf((float)r.w, wl3, al[i]);
            ar[i] = fmaf((float)r.x, wr0, ar[i]); ar[i] = fmaf((float)r.y, wr1, ar[i]);
            ar[i] = fmaf((float)r.z, wr2, ar[i]); ar[i] = fmaf((float)r.w, wr3, ar[i]);
        }
    }
#pragma unroll
    for (int i = 0; i < 16; ++i) {
        int node = node0 + nb + i;
        if (node < N) {
            xl[((size_t)node << 6) + lane] = __float2half(al[i]);
            xr[((size_t)node << 6) + lane] = __float2half(ar[i]);
        }
    }
}

// shared-memory union: xf rows (16 KB) vs partition arrays (3 KB)
union XfPartSmem {
    _Float16 rows[64 * 128];
    struct { int lh[256]; int lbase[256]; int lcur[256]; } p;
};

// FUSED: blocks [0,nbXF) = layer-1 node transform; blocks [nbXF,..) = partition
__global__ void k_xf1_part(
        const float* __restrict__ h, int ld,
        const float* __restrict__ Wl, const float* __restrict__ bl,
        const float* __restrict__ Wr, const float* __restrict__ br,
        __half* __restrict__ xl, __half* __restrict__ xr, int N, int nbXF,
        const int* __restrict__ ei, const float* __restrict__ ea,
        int* __restrict__ qtail, u64* __restrict__ queue, int E) {
    __shared__ XfPartSmem sm;
    int t = threadIdx.x;
    if (blockIdx.x < nbXF) {
        xf_block(h, ld, Wl, bl, Wr, br, xl, xr, N, blockIdx.x * 64, sm.rows, t);
    } else {
        int pb = blockIdx.x - nbXF;
        sm.p.lh[t] = 0; sm.p.lcur[t] = 0;
        __syncthreads();
        int base = pb * PEPB;
        int end = base + PEPB; if (end > E) end = E;
        for (int e = base + t; e < end; e += 256) {
            int d = ei[E + e];
            atomicAdd(&sm.p.lh[d >> 8], 1);
        }
        __syncthreads();
        if (sm.p.lh[t]) sm.p.lbase[t] = atomicAdd(&qtail[t], sm.p.lh[t]);
        __syncthreads();
        for (int e = base + t; e < end; e += 256) {
            int d = ei[E + e];
            int src = ei[e];
            float a = ea[e];
            int b = d >> 8;
            int idx = atomicAdd(&sm.p.lcur[b], 1);
            unsigned aq = (unsigned)(a * 16777216.0f);    // fixed-24, attr in [0,1)
            queue[(size_t)b * CAP + sm.p.lbase[b] + idx] =
                (((u64)aq) << 25) | (((u64)(d & 255)) << 17) | (unsigned)src;
        }
    }
}

__device__ __forceinline__ unsigned attr_q15(float a) {
    unsigned short hb = __builtin_bit_cast(unsigned short, (_Float16)a);
    return (unsigned)(hb >> 1);       // attr in [0,1) -> fp16 top bit 0
}

// one block per 256-dst bucket (196 blocks x 1024 thr):
// count+local-scan+scatter in LDS, coalesced flush; fixed csr span b*MAXSPAN.
__global__ void __launch_bounds__(1024)
k_build(const u64* __restrict__ queue, const int* __restrict__ qtail,
        u64* __restrict__ rs2, unsigned* __restrict__ csr, int N) {
    __shared__ u64 stat[256];
    __shared__ int fill[256], sc[256];
    __shared__ unsigned lcsr[MAXSPAN];
    int t = threadIdx.x, b = blockIdx.x;
    if (t < 256) stat[t] = 0;
    __syncthreads();
    int cnt = qtail[b];
    size_t q0 = (size_t)b * CAP;
    for (int i = t; i < cnt; i += 1024) {
        u64 r = queue[q0 + i];
        int dl = (int)((r >> 17) & 255);
        atomicAdd(&stat[dl], (1ULL << 32) | (unsigned)(r >> 25));
    }
    __syncthreads();
    int dg = (b << 8) + t;
    u64 p = (t < 256) ? stat[t] : 0;
    int deg = (int)(p >> 32);
    int v = (t < 256 && dg < N) ? deg + 1 : 0;
    if (t < 256) sc[t] = v;
    __syncthreads();
    for (int off = 1; off < 256; off <<= 1) {
        int a = (t >= off && t < 256) ? sc[t - off] : 0;
        __syncthreads();
        if (t < 256) sc[t] += a;
        __syncthreads();
    }
    int c0 = b * MAXSPAN;
    if (t < 256 && dg < N) {
        int basel = sc[t] - v;   // exclusive
        rs2[dg] = (u64)(unsigned)(c0 + basel) | (((u64)(unsigned)(c0 + basel + deg + 1)) << 32);
        fill[t] = basel;
        float mean = ((float)(unsigned)p * (1.0f / 16777216.0f)) / fmaxf((float)deg, 1.0f);
        if (basel + deg < MAXSPAN) lcsr[basel + deg] = (attr_q15(mean) << 17) | (unsigned)dg;
    }
    __syncthreads();
    for (int i = t; i < cnt; i += 1024) {
        u64 r = queue[q0 + i];
        int dl = (int)((r >> 17) & 255);
        int pos = atomicAdd(&fill[dl], 1);
        float av = (float)(unsigned)(r >> 25) * (1.0f / 16777216.0f);
        if (pos < MAXSPAN) lcsr[pos] = (attr_q15(av) << 17) | (unsigned)(r & 0x1FFFFu);
    }
    __syncthreads();
    int span = sc[255];               // total slots used in this bucket
    if (span > MAXSPAN) span = MAXSPAN;
    for (int j = t; j < span; j += 1024) csr[c0 + j] = lcsr[j];
}

// ---------- node transform (standalone, layer 2: ld=6 -> 8 KB rows) ----------
__global__ void k_node_xf(const float* __restrict__ h, int ld,
                          const float* __restrict__ Wl, const float* __restrict__ bl,
                          const float* __restrict__ Wr, const float* __restrict__ br,
                          __half* __restrict__ xl, __half* __restrict__ xr, int N) {
    __shared__ _Float16 rows[64 * 64];
    xf_block(h, ld, Wl, bl, Wr, br, xl, xr, N, blockIdx.x * 64, rows, threadIdx.x);
}

// ---------- edge micro-step: one 4-edge group ----------
#define EDGE_GROUP(r, xh, cc)                                                  \
    {                                                                          \
        _Float16 ah = __builtin_bit_cast(_Float16, (unsigned short)((r >> 16) & 0xFFFEu)); \
        half2v aa = {ah, ah};                                                  \
        half2v x01 = {xh.x, xh.y}, x23 = {xh.z, xh.w};                         \
        half2v v01 = aa * We01 + (x01 + xr01);                                 \
        half2v v23 = aa * We23 + (x23 + xr23);                                 \
        half2v s01 = __builtin_elementwise_max(v01, v01 * k02);                \
        half2v s23 = __builtin_elementwise_max(v23, v23 * k02);                \
        cc = __builtin_amdgcn_fdot2(s01, at01, 0.f, false);                    \
        cc = __builtin_amdgcn_fdot2(s23, at23, cc, false);                     \
    }

// ---------- fused edge phase: wave/dst, 16x4 packed fp16, unroll x4 ----------
__global__ void k_attn(const __half* __restrict__ xl, const __half* __restrict__ xr,
                       const unsigned* __restrict__ csr, const u64* __restrict__ rs2,
                       const float* __restrict__ We, const float* __restrict__ att,
                       const float* __restrict__ bias,
                       float* __restrict__ hout, int N) {
    int lane = threadIdx.x & 63;
    int d = (int)(((size_t)blockIdx.x * blockDim.x + threadIdx.x) >> 6);
    if (d >= N) return;
    int eq = lane >> 4;           // which of 4 concurrent edges
    int fl = lane & 15;           // which 4-dim chunk of the 64 dims
    float4 Wef  = *(const float4*)(We + fl * 4);
    float4 attf = *(const float4*)(att + fl * 4);
    half2v We01 = {(_Float16)Wef.x, (_Float16)Wef.y};
    half2v We23 = {(_Float16)Wef.z, (_Float16)Wef.w};
    half2v at01 = {(_Float16)attf.x, (_Float16)attf.y};
    half2v at23 = {(_Float16)attf.z, (_Float16)attf.w};
    half4v xrh = *(const half4v*)(xr + ((size_t)d << 6) + fl * 4);
    half2v xr01 = {xrh.x, xrh.y}, xr23 = {xrh.z, xrh.w};
    const half2v k02 = {(_Float16)0.2f, (_Float16)0.2f};
    u64 rr = rs2[d];
    int e0 = __builtin_amdgcn_readfirstlane((int)(unsigned)rr);
    int e1 = __builtin_amdgcn_readfirstlane((int)(unsigned)(rr >> 32));
    float l = 0.f;
    float4 O = {0.f, 0.f, 0.f, 0.f};
    int e = e0;
    for (; e + 16 <= e1; e += 16) {     // 16 edges in flight
        unsigned rA = csr[e + eq];
        unsigned rB = csr[e + 4 + eq];
        unsigned rC = csr[e + 8 + eq];
        unsigned rD = csr[e + 12 + eq];
        half4v xA = *(const half4v*)(xl + (((size_t)(rA & 0x1FFFFu)) << 6) + fl * 4);
        half4v xB = *(const half4v*)(xl + (((size_t)(rB & 0x1FFFFu)) << 6) + fl * 4);
        half4v xC = *(const half4v*)(xl + (((size_t)(rC & 0x1FFFFu)) << 6) + fl * 4);
        half4v xD = *(const half4v*)(xl + (((size_t)(rD & 0x1FFFFu)) << 6) + fl * 4);
        float cA, cB, cC, cD;
        EDGE_GROUP(rA, xA, cA);
        EDGE_GROUP(rB, xB, cB);
        EDGE_GROUP(rC, xC, cC);
        EDGE_GROUP(rD, xD, cD);
#pragma unroll
        for (int mm = 1; mm <= 8; mm <<= 1) {      // 4 interleaved butterflies
            cA += __shfl_xor(cA, mm, 64);
            cB += __shfl_xor(cB, mm, 64);
            cC += __shfl_xor(cC, mm, 64);
            cD += __shfl_xor(cD, mm, 64);
        }
        float qA = __expf(cA), qB = __expf(cB), qC = __expf(cC), qD = __expf(cD);
        l += (qA + qB) + (qC + qD);
        O.x = fmaf(qA, (float)xA.x, O.x); O.x = fmaf(qB, (float)xB.x, O.x);
        O.x = fmaf(qC, (float)xC.x, O.x); O.x = fmaf(qD, (float)xD.x, O.x);
        O.y = fmaf(qA, (float)xA.y, O.y); O.y = fmaf(qB, (float)xB.y, O.y);
        O.y = fmaf(qC, (float)xC.y, O.y); O.y = fmaf(qD, (float)xD.y, O.y);
        O.z = fmaf(qA, (float)xA.z, O.z); O.z = fmaf(qB, (float)xB.z, O.z);
        O.z = fmaf(qC, (float)xC.z, O.z); O.z = fmaf(qD, (float)xD.z, O.z);
        O.w = fmaf(qA, (float)xA.w, O.w); O.w = fmaf(qB, (float)xB.w, O.w);
        O.w = fmaf(qC, (float)xC.w, O.w); O.w = fmaf(qD, (float)xD.w, O.w);
    }
    for (; e < e1; e += 4) {            // tail with clamp
        int ee = e + eq;
        bool valid = ee < e1;
        unsigned r = csr[valid ? ee : (e1 - 1)];
        half4v xh = *(const half4v*)(xl + (((size_t)(r & 0x1FFFFu)) << 6) + fl * 4);
        float c;
        EDGE_GROUP(r, xh, c);
#pragma unroll
        for (int mm = 1; mm <= 8; mm <<= 1) c += __shfl_xor(c, mm, 64);
        float q = valid ? __expf(c) : 0.f;
        l += q;
        O.x = fmaf(q, (float)xh.x, O.x);
        O.y = fmaf(q, (float)xh.y, O.y);
        O.z = fmaf(q, (float)xh.z, O.z);
        O.w = fmaf(q, (float)xh.w, O.w);
    }
#pragma unroll
    for (int mm = 16; mm <= 32; mm <<= 1) {
        l   += __shfl_xor(l, mm, 64);
        O.x += __shfl_xor(O.x, mm, 64);
        O.y += __shfl_xor(O.y, mm, 64);
        O.z += __shfl_xor(O.z, mm, 64);
        O.w += __shfl_xor(O.w, mm, 64);
    }
    if (eq == 0) {
        float inv = 1.0f / (l + 1e-16f);
        float4 b4 = *(const float4*)(bias + fl * 4);
        float4 res;
        res.x = fmaf(O.x, inv, b4.x);
        res.y = fmaf(O.y, inv, b4.y);
        res.z = fmaf(O.z, inv, b4.z);
        res.w = fmaf(O.w, inv, b4.w);
        res.x = res.x > 0.f ? res.x : expm1f(res.x);
        res.y = res.y > 0.f ? res.y : expm1f(res.y);
        res.z = res.z > 0.f ? res.z : expm1f(res.z);
        res.w = res.w > 0.f ? res.w : expm1f(res.w);
        *(float4*)(hout + ((size_t)d << 6) + fl * 4) = res;
    }
}

// ---------- pool (+ fused head in last-done block) ----------
__global__ void k_pool_head(const float* __restrict__ h, const int* __restrict__ batch,
                            float* __restrict__ pooled, float* __restrict__ gcnt,
                            int N, int npw, int* __restrict__ done,
                            const float* __restrict__ W1, const float* __restrict__ b1,
                            const float* __restrict__ gam, const float* __restrict__ bet,
                            const float* __restrict__ mu, const float* __restrict__ var,
                            const float* __restrict__ W3, const float* __restrict__ b3,
                            float* __restrict__ out, int G) {
    int tid = threadIdx.x;
    int lane = tid & 63;
    int wave = (int)(((size_t)blockIdx.x * blockDim.x + tid) >> 6);
    int begin = wave * npw;
    if (begin < N) {
        int end = begin + npw; if (end > N) end = N;
        int g = batch[begin];
        float acc = 0.f, cnt = 0.f;
        for (int n = begin; n < end; ++n) {
            int gn = batch[n];
            if (gn != g) {
                atomicAdd(&pooled[((size_t)g << 6) + lane], acc);
                if (lane == 0) atomicAdd(&gcnt[g], cnt);
                g = gn; acc = 0.f; cnt = 0.f;
            }
            acc += h[((size_t)n << 6) + lane];
            cnt += 1.f;
        }
        atomicAdd(&pooled[((size_t)g << 6) + lane], acc);
        if (lane == 0) atomicAdd(&gcnt[g], cnt);
    }
    __threadfence();
    __syncthreads();
    __shared__ int lastFlag;
    if (tid == 0) lastFlag = (atomicAdd(done, 1) == (int)gridDim.x - 1);
    __syncthreads();
    if (lastFlag && tid < G) {
        __threadfence();
        int g = tid;
        float inv = 1.0f / fmaxf(gcnt[g], 1.0f);
        float pr[64];
        for (int k = 0; k < 64; ++k) pr[k] = pooled[((size_t)g << 6) + k] * inv;
        float o = b3[0];
        for (int j = 0; j < 32; ++j) {
            float z = b1[j];
            for (int k = 0; k < 64; ++k) z += pr[k] * W1[k * 32 + j];
            z = fmaxf(z, 0.f);
            z = (z - mu[j]) / sqrtf(var[j] + 1e-5f) * gam[j] + bet[j];
            o += z * W3[j];
        }
        out[g] = o;
    }
}

// ---------- launch ----------
extern "C" void kernel_launch(void* const* d_in, const int* in_sizes, int n_in,
                              void* d_out, int out_size, void* d_ws, size_t ws_size,
                              hipStream_t stream) {
    const float* x    = (const float*)d_in[0];
    const int*   ei   = (const int*)d_in[1];
    const float* ea   = (const float*)d_in[2];
    const int*   batch= (const int*)d_in[3];
    const float* Wl1  = (const float*)d_in[4];
    const float* bl1  = (const float*)d_in[5];
    const float* Wr1  = (const float*)d_in[6];
    const float* br1  = (const float*)d_in[7];
    const float* We1  = (const float*)d_in[8];
    const float* att1 = (const float*)d_in[9];
    const float* bi1  = (const float*)d_in[10];
    const float* Wl2  = (const float*)d_in[11];
    const float* bl2  = (const float*)d_in[12];
    const float* Wr2  = (const float*)d_in[13];
    const float* br2  = (const float*)d_in[14];
    const float* We2  = (const float*)d_in[15];
    const float* att2 = (const float*)d_in[16];
    const float* bi2  = (const float*)d_in[17];
    const float* Wf1  = (const float*)d_in[18];
    const float* bf1  = (const float*)d_in[19];
    const float* gam  = (const float*)d_in[20];
    const float* bet  = (const float*)d_in[21];
    const float* mu   = (const float*)d_in[22];
    const float* var  = (const float*)d_in[23];
    const float* Wf3  = (const float*)d_in[24];
    const float* bf3  = (const float*)d_in[25];

    const int N    = in_sizes[3];          // 50000
    const int E    = in_sizes[2];          // 1600000
    const int INd  = in_sizes[0] / N;      // 128
    const int ld1  = (INd == 128) ? 7 : 6;
    const int G    = out_size;             // 64
    const int NB   = (N + 255) / 256;      // 256-dst buckets (196)

    // workspace carve-up (256B aligned)
    char* w = (char*)d_ws;
    auto carve = [&](size_t bytes) { char* p = w; w += (bytes + 255) & ~(size_t)255; return p; };
    __half*   xl       = (__half*)  carve((size_t)N * 64 * 2);
    __half*   xr       = (__half*)  carve((size_t)N * 64 * 2);
    float*    hbuf     = (float*)   carve((size_t)N * 64 * 4);
    unsigned* csr      = (unsigned*)carve((size_t)NB * MAXSPAN * 4);
    u64*      queue    = (u64*)     carve((size_t)NB * CAP * 8);
    u64*      rs2      = (u64*)     carve((size_t)N * 8);
    int*      qtail    = (int*)     carve((size_t)(NB + 1) * 4);
    float*    pooled   = (float*)   carve((size_t)G * 64 * 4);   // contiguous with
    float*    gcnt     = (float*)   carve((size_t)G * 4);        // gcnt and done:
    int*      done     = (int*)     carve(256);                  // single memset

    const int TB = 256;
    const int nbXF = (N + 63) / 64;              // node-transform blocks
    const int attnBlocks = (N + 3) / 4;          // wave per dst, 4 waves/block
    const int nbPart = (E + PEPB - 1) / PEPB;    // 391 partition blocks

    // ---- zero counters ----
    hipMemsetAsync(qtail, 0, (size_t)(NB + 1) * 4, stream);
    size_t poolRegion = (((size_t)G * 64 * 4 + 255) & ~(size_t)255)
                      + (((size_t)G * 4 + 255) & ~(size_t)255) + 256;
    hipMemsetAsync(pooled, 0, poolRegion, stream);

    // ---- fused: layer-1 node transform || edge partition ----
    k_xf1_part<<<nbXF + nbPart, TB, 0, stream>>>(x, ld1, Wl1, bl1, Wr1, br1, xl, xr, N, nbXF,
                                                 ei, ea, qtail, queue, E);
    k_build<<<NB, 1024, 0, stream>>>(queue, qtail, rs2, csr, N);

    // ---- layer 1 edge phase ----
    k_attn<<<attnBlocks, TB, 0, stream>>>(xl, xr, csr, rs2, We1, att1, bi1, hbuf, N);

    // ---- layer 2 ----
    k_node_xf<<<nbXF, TB, 0, stream>>>(hbuf, 6, Wl2, bl2, Wr2, br2, xl, xr, N);
    k_attn<<<attnBlocks, TB, 0, stream>>>(xl, xr, csr, rs2, We2, att2, bi2, hbuf, N);

    // ---- pool + head (fused) ----
    const int npw = 64;
    const int poolWaves = (N + npw - 1) / npw;
    k_pool_head<<<(poolWaves * 64 + TB - 1) / TB, TB, 0, stream>>>(
        hbuf, batch, pooled, gcnt, N, npw, done,
        Wf1, bf1, gam, bet, mu, var, Wf3, bf3, (float*)d_out, G);
}